// Round 5
// baseline (944.817 us; speedup 1.0000x reference)
//
#include <hip/hip_runtime.h>
#include <hip/hip_bf16.h>

typedef __bf16 bf16x8 __attribute__((ext_vector_type(8)));
typedef float  f32x4  __attribute__((ext_vector_type(4)));
typedef unsigned short u16;
typedef unsigned short u16x4 __attribute__((ext_vector_type(4)));
typedef unsigned long long u64;

#define NB 1024
#define NS 1024
#define NI 32
#define NH 128

__device__ __forceinline__ u64 pack4_bf16(f32x4 v) {
  u16x4 p;
#pragma unroll
  for (int r = 0; r < 4; ++r) p[r] = __builtin_bit_cast(u16, (__bf16)v[r]);
  return __builtin_bit_cast(u64, p);
}

// Barrier that drains lgkmcnt only (no vmcnt): global stores stay in flight.
__device__ __forceinline__ void lds_barrier() {
  __builtin_amdgcn_sched_barrier(0);
  asm volatile("s_waitcnt lgkmcnt(0)" ::: "memory");
  __builtin_amdgcn_s_barrier();
  asm volatile("" ::: "memory");
  __builtin_amdgcn_sched_barrier(0);
}

// Block: 512 threads = 8 waves (2/SIMD). Block owns 32 batch rows = TWO independent
// 16-row chains (A = rows rb..rb+15, B = rb+16..rb+31), interleaved in-wave so the
// chains' MFMA / trans / VALU phases overlap across pipes (they are independent).
// Wave w computes hidden cols [16w, 16w+16) for BOTH chains.
// MFMA: D'[n][m] = sum_k U[k][n] * h[m][k]  (A' = U^T slice, B' = h^T)
//   B'-frag: lane l holds h[m=l&15][k = 32kt + 8(l>>4) + j]   (one ds_read_b128)
//   D'     : lane l holds h_new[m=l&15][n = 16w + 4(l>>4) + r]
// h ping-pongs in LDS as bf16 (u64 units swizzled by unit ^ ((row&7)<<1)).
__global__ __launch_bounds__(512, 2) void gru_scan(
    const float* __restrict__ x,
    const float* __restrict__ Wz, const float* __restrict__ Uz, const float* __restrict__ bz,
    const float* __restrict__ Wh, const float* __restrict__ Uh, const float* __restrict__ bh,
    float* __restrict__ out)
{
  __shared__ __align__(16) u64    hbuf[2][2][16][32];      // [chain][buf] 16 KB
  __shared__ __align__(16) bf16x8 xbuf[2][2][8][16][4];    // [chain][buf] 32 KB

  const int tid  = threadIdx.x;
  const int lane = tid & 63;
  const int w    = tid >> 6;     // wave 0..7
  const int ml   = lane & 15;    // batch row within chain tile
  const int g    = lane >> 4;    // k-group / reg-group
  const int rb   = blockIdx.x * 32;

  // ---- persistent weight fragments (shared by both chains) ----
  bf16x8 ufrag[2][4];   // [gate][kt]
  bf16x8 wfrag[2];      // [gate]
  f32x4  bias2[2];      // [gate], D layout
  {
    const float* Ug[2] = {Uz, Uh};
    const float* Wg[2] = {Wz, Wh};
    const float* bg[2] = {bz, bh};
    const int n0 = 16 * w + ml;
#pragma unroll
    for (int gate = 0; gate < 2; ++gate) {
#pragma unroll
      for (int kt = 0; kt < 4; ++kt)
#pragma unroll
        for (int j = 0; j < 8; ++j)
          ufrag[gate][kt][j] = (__bf16)Ug[gate][(32 * kt + 8 * g + j) * NH + n0];
#pragma unroll
      for (int j = 0; j < 8; ++j)
        wfrag[gate][j] = (__bf16)Wg[gate][(8 * g + j) * NH + n0];
      const int nb = 16 * w + 4 * g;
#pragma unroll
      for (int r = 0; r < 4; ++r) bias2[gate][r] = bg[gate][nb + r];
    }
  }

  // h0 = 0 for both chains
  for (int i = tid; i < 2 * 16 * 32; i += 512)
    hbuf[i >> 9][0][(i >> 5) & 15][i & 31] = 0ULL;

  // ---- x staging: thread (r_st, c8) handles one 16B bf16 unit per chain per chunk ----
  const int r_st  = tid >> 5;          // 0..15
  const int c8    = tid & 31;          // step tt = c8>>2, unit = c8&3
  const int tt_st = c8 >> 2;
  const int un_st = (c8 & 3) ^ (r_st & 3);
  const float* xbaseA = x + (size_t)(rb + r_st) * (NS * NI) + c8 * 8;
  const float* xbaseB = x + (size_t)(rb + 16 + r_st) * (NS * NI) + c8 * 8;

  {  // stage chunk 0, both chains
    f32x4 a0 = *(const f32x4*)(xbaseA);
    f32x4 a1 = *(const f32x4*)(xbaseA + 4);
    f32x4 b0 = *(const f32x4*)(xbaseB);
    f32x4 b1 = *(const f32x4*)(xbaseB + 4);
    bf16x8 uA, uB;
#pragma unroll
    for (int j = 0; j < 4; ++j) {
      uA[j] = (__bf16)a0[j]; uA[4 + j] = (__bf16)a1[j];
      uB[j] = (__bf16)b0[j]; uB[4 + j] = (__bf16)b1[j];
    }
    xbuf[0][0][tt_st][r_st][un_st] = uA;
    xbuf[1][0][tt_st][r_st][un_st] = uB;
  }
  __syncthreads();   // cold path: full drain fine

  // per-lane LDS constants
  const int sw = (ml & 7) << 1;
  int ridx[4];
#pragma unroll
  for (int kt = 0; kt < 4; ++kt) ridx[kt] = (8 * kt + 2 * g) ^ sw;  // even -> b128 ok
  const int widx = (4 * w + g) ^ sw;
  const int xidx = g ^ (ml & 3);

  f32x4 hvA = {0.f, 0.f, 0.f, 0.f};
  f32x4 hvB = {0.f, 0.f, 0.f, 0.f};
  float* optrA = out + (size_t)(rb + ml) * NS * NH + 16 * w + 4 * g;
  float* optrB = out + (size_t)(rb + 16 + ml) * NS * NH + 16 * w + 4 * g;

  f32x4 vA0, vA1, vB0, vB1;  // x prefetch regs (one chunk unit per chain)
  const float NL2E  = -1.4426950408889634f;  // -log2(e)
  const float P2L2E =  2.8853900817779268f;  //  2*log2(e)
  const f32x4 zero4 = {0.f, 0.f, 0.f, 0.f};

  // One interleaved step of BOTH chains. P = tt&1 (compile-time), XB = chunk&1.
#define GRU_STEP2(P, XB, TT)                                                               \
  {                                                                                        \
    const u64* hrA = &hbuf[0][P][ml][0];                                                   \
    const u64* hrB = &hbuf[1][P][ml][0];                                                   \
    /* reads: x frags first, then h frags (in-order lgkm cascade) */                       \
    bf16x8 xfA = xbuf[0][XB][TT][ml][xidx];                                                \
    bf16x8 xfB = xbuf[1][XB][TT][ml][xidx];                                                \
    bf16x8 a0 = *(const bf16x8*)(hrA + ridx[0]);                                           \
    bf16x8 a1 = *(const bf16x8*)(hrA + ridx[1]);                                           \
    bf16x8 a2 = *(const bf16x8*)(hrA + ridx[2]);                                           \
    bf16x8 a3 = *(const bf16x8*)(hrA + ridx[3]);                                           \
    bf16x8 b0 = *(const bf16x8*)(hrB + ridx[0]);                                           \
    bf16x8 b1 = *(const bf16x8*)(hrB + ridx[1]);                                           \
    bf16x8 b2 = *(const bf16x8*)(hrB + ridx[2]);                                           \
    bf16x8 b3 = *(const bf16x8*)(hrB + ridx[3]);                                           \
    /* ax = bias + x@W (needs only xf; runs while h reads are in flight) */                \
    f32x4 azA = __builtin_amdgcn_mfma_f32_16x16x32_bf16(wfrag[0], xfA, bias2[0], 0, 0, 0); \
    f32x4 ahA = __builtin_amdgcn_mfma_f32_16x16x32_bf16(wfrag[1], xfA, bias2[1], 0, 0, 0); \
    f32x4 azB = __builtin_amdgcn_mfma_f32_16x16x32_bf16(wfrag[0], xfB, bias2[0], 0, 0, 0); \
    f32x4 ahB = __builtin_amdgcn_mfma_f32_16x16x32_bf16(wfrag[1], xfB, bias2[1], 0, 0, 0); \
    /* chain A h-MFMAs: 4 independent chains of 2 */                                       \
    f32x4 z1A = __builtin_amdgcn_mfma_f32_16x16x32_bf16(ufrag[0][0], a0, azA,   0, 0, 0);  \
    f32x4 h1A = __builtin_amdgcn_mfma_f32_16x16x32_bf16(ufrag[1][0], a0, ahA,   0, 0, 0);  \
    f32x4 z2A = __builtin_amdgcn_mfma_f32_16x16x32_bf16(ufrag[0][2], a2, zero4, 0, 0, 0);  \
    f32x4 h2A = __builtin_amdgcn_mfma_f32_16x16x32_bf16(ufrag[1][2], a2, zero4, 0, 0, 0);  \
    z1A = __builtin_amdgcn_mfma_f32_16x16x32_bf16(ufrag[0][1], a1, z1A, 0, 0, 0);          \
    h1A = __builtin_amdgcn_mfma_f32_16x16x32_bf16(ufrag[1][1], a1, h1A, 0, 0, 0);          \
    z2A = __builtin_amdgcn_mfma_f32_16x16x32_bf16(ufrag[0][3], a3, z2A, 0, 0, 0);          \
    h2A = __builtin_amdgcn_mfma_f32_16x16x32_bf16(ufrag[1][3], a3, h2A, 0, 0, 0);          \
    /* chain B h-MFMAs */                                                                  \
    f32x4 z1B = __builtin_amdgcn_mfma_f32_16x16x32_bf16(ufrag[0][0], b0, azB,   0, 0, 0);  \
    f32x4 h1B = __builtin_amdgcn_mfma_f32_16x16x32_bf16(ufrag[1][0], b0, ahB,   0, 0, 0);  \
    f32x4 z2B = __builtin_amdgcn_mfma_f32_16x16x32_bf16(ufrag[0][2], b2, zero4, 0, 0, 0);  \
    f32x4 h2B = __builtin_amdgcn_mfma_f32_16x16x32_bf16(ufrag[1][2], b2, zero4, 0, 0, 0);  \
    z1B = __builtin_amdgcn_mfma_f32_16x16x32_bf16(ufrag[0][1], b1, z1B, 0, 0, 0);          \
    h1B = __builtin_amdgcn_mfma_f32_16x16x32_bf16(ufrag[1][1], b1, h1B, 0, 0, 0);          \
    z2B = __builtin_amdgcn_mfma_f32_16x16x32_bf16(ufrag[0][3], b3, z2B, 0, 0, 0);          \
    h2B = __builtin_amdgcn_mfma_f32_16x16x32_bf16(ufrag[1][3], b3, h2B, 0, 0, 0);          \
    /* elementwise A (overlaps B's matrix-pipe time) */                                    \
    f32x4 hnA, hnB;                                                                        \
    {                                                                                      \
      const f32x4 az = z1A + z2A;                                                          \
      const f32x4 ah = h1A + h2A;                                                          \
      _Pragma("unroll")                                                                    \
      for (int r = 0; r < 4; ++r) {                                                        \
        float ez = __builtin_amdgcn_exp2f(az[r] * NL2E);                                   \
        float zz = __builtin_amdgcn_rcpf(1.f + ez);                                        \
        float eh = __builtin_amdgcn_exp2f(ah[r] * P2L2E);                                  \
        float th = 1.f - 2.f * __builtin_amdgcn_rcpf(1.f + eh);                            \
        hnA[r] = __builtin_fmaf(zz, th - hvA[r], hvA[r]);                                  \
      }                                                                                    \
    }                                                                                      \
    hbuf[0][P ^ 1][ml][widx] = pack4_bf16(hnA);                                            \
    {                                                                                      \
      const f32x4 az = z1B + z2B;                                                          \
      const f32x4 ah = h1B + h2B;                                                          \
      _Pragma("unroll")                                                                    \
      for (int r = 0; r < 4; ++r) {                                                        \
        float ez = __builtin_amdgcn_exp2f(az[r] * NL2E);                                   \
        float zz = __builtin_amdgcn_rcpf(1.f + ez);                                        \
        float eh = __builtin_amdgcn_exp2f(ah[r] * P2L2E);                                  \
        float th = 1.f - 2.f * __builtin_amdgcn_rcpf(1.f + eh);                            \
        hnB[r] = __builtin_fmaf(zz, th - hvB[r], hvB[r]);                                  \
      }                                                                                    \
    }                                                                                      \
    hbuf[1][P ^ 1][ml][widx] = pack4_bf16(hnB);                                            \
    hvA = hnA; hvB = hnB;                                                                  \
    __builtin_nontemporal_store(hnA, (f32x4*)optrA); optrA += NH;                          \
    __builtin_nontemporal_store(hnB, (f32x4*)optrB); optrB += NH;                          \
  }

  for (int chunk = 0; chunk < NS / 8; ++chunk) {
    const int  xb   = chunk & 1;
    const bool more = (chunk + 1 < NS / 8);
#pragma unroll
    for (int tt = 0; tt < 8; ++tt) {
      if (tt == 0 && more) {  // issue next chunk's x loads (~6 steps of cover)
        const float* pA = xbaseA + (size_t)(chunk + 1) * (8 * NI);
        const float* pB = xbaseB + (size_t)(chunk + 1) * (8 * NI);
        vA0 = *(const f32x4*)(pA); vA1 = *(const f32x4*)(pA + 4);
        vB0 = *(const f32x4*)(pB); vB1 = *(const f32x4*)(pB + 4);
      }

      if (tt & 1) { GRU_STEP2(1, xb, tt) } else { GRU_STEP2(0, xb, tt) }

      if (tt == 6 && more) {  // convert + write next x chunk, both chains
        bf16x8 uA, uB;
#pragma unroll
        for (int j = 0; j < 4; ++j) {
          uA[j] = (__bf16)vA0[j]; uA[4 + j] = (__bf16)vA1[j];
          uB[j] = (__bf16)vB0[j]; uB[4 + j] = (__bf16)vB1[j];
        }
        xbuf[0][xb ^ 1][tt_st][r_st][un_st] = uA;
        xbuf[1][xb ^ 1][tt_st][r_st][un_st] = uB;
      }

      lds_barrier();   // one barrier advances both chains
    }
  }

  // h_last for both chains
  const size_t lbaseA = (size_t)NB * NS * NH + (size_t)(rb + ml) * NH + 16 * w + 4 * g;
  const size_t lbaseB = (size_t)NB * NS * NH + (size_t)(rb + 16 + ml) * NH + 16 * w + 4 * g;
  *(f32x4*)(out + lbaseA) = hvA;
  *(f32x4*)(out + lbaseB) = hvB;
}

extern "C" void kernel_launch(void* const* d_in, const int* in_sizes, int n_in,
                              void* d_out, int out_size, void* d_ws, size_t ws_size,
                              hipStream_t stream) {
  const float* x  = (const float*)d_in[0];
  // d_in[1..3] = W_r, U_r, b_r: unused (r gate never affects the output)
  const float* Wz = (const float*)d_in[4];
  const float* Uz = (const float*)d_in[5];
  const float* bz = (const float*)d_in[6];
  const float* Wh = (const float*)d_in[7];
  const float* Uh = (const float*)d_in[8];
  const float* bh = (const float*)d_in[9];
  float* out = (float*)d_out;

  gru_scan<<<dim3(NB / 32), dim3(512), 0, stream>>>(x, Wz, Uz, bz, Wh, Uh, bh, out);
}

// Round 6
// 490.644 us; speedup vs baseline: 1.9257x; 1.9257x over previous
//
#include <hip/hip_runtime.h>
#include <hip/hip_bf16.h>

typedef __bf16 bf16x8 __attribute__((ext_vector_type(8)));
typedef float  f32x4  __attribute__((ext_vector_type(4)));
typedef unsigned short u16;
typedef unsigned short u16x4 __attribute__((ext_vector_type(4)));
typedef unsigned long long u64;

#define NB 1024
#define NS 1024
#define NI 32
#define NH 128

__device__ __forceinline__ u64 pack4_bf16(f32x4 v) {
  u16x4 p;
#pragma unroll
  for (int r = 0; r < 4; ++r) p[r] = __builtin_bit_cast(u16, (__bf16)v[r]);
  return __builtin_bit_cast(u64, p);
}

// Barrier that drains lgkmcnt only (no vmcnt): global stores stay in flight.
__device__ __forceinline__ void lds_barrier() {
  __builtin_amdgcn_sched_barrier(0);
  asm volatile("s_waitcnt lgkmcnt(0)" ::: "memory");
  __builtin_amdgcn_s_barrier();
  asm volatile("" ::: "memory");
  __builtin_amdgcn_sched_barrier(0);
}

// Block: 512 threads = 8 waves (2/SIMD). Block owns 16 batch rows for the whole scan.
// Wave w computes hidden cols [16w, 16w+16).
// MFMA: D'[n][m] = sum_k U[k][n] * h[m][k]  (A' = U^T slice, B' = h^T)
//   B'-frag: lane l holds h[m=l&15][k = 32kt + 8(l>>4) + j]   (one ds_read_b128)
//   D'     : lane l holds h_new[m=l&15][n = 16w + 4(l>>4) + r]
//
// LDS layouts are k-major with odd row padding so every b128 read is bank-uniform
// (quad index = (ku + ml) mod 8; exactly 8 lanes per 4-bank quad = the floor):
//   hb[buf][ku 0..15][ml 0..16][half]   : h tile, unit ku = k/8, 17-row pad
//   hx[buf][tt][ku 0..3][ml 0..16][half]: x tile per step-slot, same padding
__global__ __launch_bounds__(512, 2) void gru_scan(
    const float* __restrict__ x,
    const float* __restrict__ Wz, const float* __restrict__ Uz, const float* __restrict__ bz,
    const float* __restrict__ Wh, const float* __restrict__ Uh, const float* __restrict__ bh,
    float* __restrict__ out)
{
  __shared__ __align__(16) u64 hb[2][16][17][2];       // 8.5 KB
  __shared__ __align__(16) u64 hx[2][8][4][17][2];     // 17 KB

  const int tid  = threadIdx.x;
  const int lane = tid & 63;
  const int w    = tid >> 6;     // wave 0..7
  const int ml   = lane & 15;    // batch row in tile
  const int g    = lane >> 4;    // k-group / reg-group
  const int rb   = blockIdx.x * 16;

  // ---- persistent weight fragments ----
  bf16x8 ufrag[2][4];   // [gate][kt]
  bf16x8 wfrag[2];      // [gate]
  f32x4  bias2[2];      // [gate], D layout
  {
    const float* Ug[2] = {Uz, Uh};
    const float* Wg[2] = {Wz, Wh};
    const float* bg[2] = {bz, bh};
    const int n0 = 16 * w + ml;   // A'-row = hidden col
#pragma unroll
    for (int gate = 0; gate < 2; ++gate) {
#pragma unroll
      for (int kt = 0; kt < 4; ++kt)
#pragma unroll
        for (int j = 0; j < 8; ++j)
          ufrag[gate][kt][j] = (__bf16)Ug[gate][(32 * kt + 8 * g + j) * NH + n0];
#pragma unroll
      for (int j = 0; j < 8; ++j)
        wfrag[gate][j] = (__bf16)Wg[gate][(8 * g + j) * NH + n0];
      const int nb = 16 * w + 4 * g;
#pragma unroll
      for (int r = 0; r < 4; ++r) bias2[gate][r] = bg[gate][nb + r];
    }
  }

  // h0 = 0
  for (int i = tid; i < 16 * 17 * 2; i += 512) ((u64*)hb[0])[i] = 0ULL;

  // ---- x staging: thread (r_st, c8) handles 8 consecutive floats (one 16B unit) ----
  const int r_st  = tid >> 5;          // 0..15
  const int c8    = tid & 31;          // 0..31: tt = c8>>2, ku = c8&3
  const int tt_st = c8 >> 2;
  const int ku_st = c8 & 3;
  const float* xbase = x + (size_t)(rb + r_st) * (NS * NI) + c8 * 8;

  {  // stage chunk 0
    f32x4 a0 = *(const f32x4*)(xbase);
    f32x4 a1 = *(const f32x4*)(xbase + 4);
    bf16x8 u;
#pragma unroll
    for (int j = 0; j < 4; ++j) { u[j] = (__bf16)a0[j]; u[4 + j] = (__bf16)a1[j]; }
    *(bf16x8*)&hx[0][tt_st][ku_st][r_st][0] = u;
  }
  __syncthreads();   // cold path: full drain fine

  // per-lane offsets
  const int woff_ku = 2 * w + (g >> 1);    // write unit for this wave's 4 cols
  const int whalf   = g & 1;

  f32x4 hv = {0.f, 0.f, 0.f, 0.f};
  float* optr = out + (size_t)(rb + ml) * NS * NH + 16 * w + 4 * g;

  f32x4 vxa, vxb;  // x global prefetch
  const float NL2E  = -1.4426950408889634f;  // -log2(e)
  const float P2L2E =  2.8853900817779268f;  //  2*log2(e)
  const f32x4 zero4 = {0.f, 0.f, 0.f, 0.f};

  // ax (= bias + x@W) for t = 0
  f32x4 axz, axh;
  {
    bf16x8 xf = *(const bf16x8*)&hx[0][0][g][ml][0];
    axz = __builtin_amdgcn_mfma_f32_16x16x32_bf16(wfrag[0], xf, bias2[0], 0, 0, 0);
    axh = __builtin_amdgcn_mfma_f32_16x16x32_bf16(wfrag[1], xf, bias2[1], 0, 0, 0);
  }

  // One step. P = t&1 compile-time. Consumes ax(t); produces ax(t+1).
  // x-frag for t+1 is stable at read time for every tt (written >= one barrier ago),
  // so it joins the post-barrier read burst.
#define GRU_STEP(P, XB, TT)                                                                \
  {                                                                                        \
    /* post-barrier read burst: 4 h frags + 1 x frag, all bank-uniform */                  \
    bf16x8 hf0 = *(const bf16x8*)&hb[P][ 0 + g][ml][0];                                    \
    bf16x8 hf1 = *(const bf16x8*)&hb[P][ 4 + g][ml][0];                                    \
    bf16x8 hf2 = *(const bf16x8*)&hb[P][ 8 + g][ml][0];                                    \
    bf16x8 hf3 = *(const bf16x8*)&hb[P][12 + g][ml][0];                                    \
    const int nxb = ((TT) == 7) ? (XB) ^ 1 : (XB);                                         \
    const int ntt = ((TT) + 1) & 7;                                                        \
    bf16x8 xf = *(const bf16x8*)&hx[nxb][ntt][g][ml][0];                                   \
    /* h-dependent MFMAs: 4 independent chains of 2 */                                     \
    f32x4 z1 = __builtin_amdgcn_mfma_f32_16x16x32_bf16(ufrag[0][0], hf0, axz,   0, 0, 0);  \
    f32x4 h1 = __builtin_amdgcn_mfma_f32_16x16x32_bf16(ufrag[1][0], hf0, axh,   0, 0, 0);  \
    f32x4 z2 = __builtin_amdgcn_mfma_f32_16x16x32_bf16(ufrag[0][2], hf2, zero4, 0, 0, 0);  \
    f32x4 h2 = __builtin_amdgcn_mfma_f32_16x16x32_bf16(ufrag[1][2], hf2, zero4, 0, 0, 0);  \
    z1 = __builtin_amdgcn_mfma_f32_16x16x32_bf16(ufrag[0][1], hf1, z1, 0, 0, 0);           \
    h1 = __builtin_amdgcn_mfma_f32_16x16x32_bf16(ufrag[1][1], hf1, h1, 0, 0, 0);           \
    z2 = __builtin_amdgcn_mfma_f32_16x16x32_bf16(ufrag[0][3], hf3, z2, 0, 0, 0);           \
    h2 = __builtin_amdgcn_mfma_f32_16x16x32_bf16(ufrag[1][3], hf3, h2, 0, 0, 0);           \
    /* ax for t+1 (independent; fills MFMA/trans shadow) */                                \
    axz = __builtin_amdgcn_mfma_f32_16x16x32_bf16(wfrag[0], xf, bias2[0], 0, 0, 0);        \
    axh = __builtin_amdgcn_mfma_f32_16x16x32_bf16(wfrag[1], xf, bias2[1], 0, 0, 0);        \
    const f32x4 az = z1 + z2;                                                              \
    const f32x4 ah = h1 + h2;                                                              \
    /* z = sigmoid(az); hh = tanh(ah); h += z*(hh-h) */                                    \
    f32x4 hn;                                                                              \
    _Pragma("unroll")                                                                      \
    for (int r = 0; r < 4; ++r) {                                                          \
      float ez = __builtin_amdgcn_exp2f(az[r] * NL2E);                                     \
      float zz = __builtin_amdgcn_rcpf(1.f + ez);                                          \
      float eh = __builtin_amdgcn_exp2f(ah[r] * P2L2E);                                    \
      float th = 1.f - 2.f * __builtin_amdgcn_rcpf(1.f + eh);                              \
      hn[r] = __builtin_fmaf(zz, th - hv[r], hv[r]);                                       \
    }                                                                                      \
    hv = hn;                                                                               \
    /* publish bf16 h(t+1) to the other buffer */                                          \
    hb[P ^ 1][woff_ku][ml][whalf] = pack4_bf16(hn);                                        \
    /* stream hidden_seq[b, t, :] — stays in flight across the barrier */                  \
    __builtin_nontemporal_store(hn, (f32x4*)optr);                                         \
    optr += NH;                                                                            \
  }

  for (int chunk = 0; chunk < NS / 8; ++chunk) {
    const int  xb   = chunk & 1;
    const bool more = (chunk + 1 < NS / 8);
#pragma unroll
    for (int tt = 0; tt < 8; ++tt) {
      if (tt == 0 && more) {  // issue next chunk's x loads (~6 steps of cover)
        const float* p = xbase + (size_t)(chunk + 1) * (8 * NI);
        vxa = *(const f32x4*)(p);
        vxb = *(const f32x4*)(p + 4);
      }

      if (tt & 1) { GRU_STEP(1, xb, tt) } else { GRU_STEP(0, xb, tt) }

      if (tt == 6 && more) {  // convert + write next x chunk
        bf16x8 u;
#pragma unroll
        for (int j = 0; j < 4; ++j) { u[j] = (__bf16)vxa[j]; u[4 + j] = (__bf16)vxb[j]; }
        *(bf16x8*)&hx[xb ^ 1][tt_st][ku_st][r_st][0] = u;
      }

      lds_barrier();   // lgkmcnt(0) + s_barrier only; no vmcnt drain
    }
  }

  // h_last
  const size_t lbase = (size_t)NB * NS * NH + (size_t)(rb + ml) * NH + 16 * w + 4 * g;
  *(f32x4*)(out + lbase) = hv;
}

extern "C" void kernel_launch(void* const* d_in, const int* in_sizes, int n_in,
                              void* d_out, int out_size, void* d_ws, size_t ws_size,
                              hipStream_t stream) {
  const float* x  = (const float*)d_in[0];
  // d_in[1..3] = W_r, U_r, b_r: unused (r gate never affects the output)
  const float* Wz = (const float*)d_in[4];
  const float* Uz = (const float*)d_in[5];
  const float* bz = (const float*)d_in[6];
  const float* Wh = (const float*)d_in[7];
  const float* Uh = (const float*)d_in[8];
  const float* bh = (const float*)d_in[9];
  float* out = (float*)d_out;

  gru_scan<<<dim3(NB / 16), dim3(512), 0, stream>>>(x, Wz, Uz, bz, Wh, Uh, bh, out);
}